// Round 9
// baseline (480.132 us; speedup 1.0000x reference)
//
#include <hip/hip_runtime.h>
#include <hip/hip_bf16.h>

// CGCNN: B=16, N=1024, M=12, F=64, BF=128, 3 conv layers.
// bond is layer-invariant -> ONE bf16 MFMA GEMM produces core+filt for all
// 3 layers. Conv phase (3x atomproj + 3x layer_ep + final dense) is ONE
// plain kernel with a hierarchical device-scope grid barrier.
//
// Ledger: R3 split-launch 280us (gemm 80 @ (256,2)/VGPR128 — the ONLY clean
//   codegen for this body; (256,3)->84 VGPR spill (R8), 1024-thd->64 (R4)).
// R7: fused conv_all CORRECT but 576us — 6 barriers x ~90us: 768 serialized
//   cross-XCD RMWs on ONE cacheline (~117ns each). Conv WORK measured ~36us;
//   split-launch boundaries cost ~150us -> fusion is the right lever.
// R9: R7 verbatim except the barrier: 8 group counters on separate 128B
//   lines (grp=blockIdx&7, 96 arrivals each, parallel across lines) ->
//   root flag (8 RMWs) -> spinners poll root with s_sleep backoff.

#define BB 16
#define NN 1024
#define MM 12
#define FF 64
#define BFE 128
#define RT (BB * NN * MM)   // 196608 bond rows
#define S_BN 0.99950037f    // 1/sqrt(1+1e-3)
#define WCOLS 208           // 192 core cols (3 layers x 64) + 3 filt + 13 pad
#define WSTR 136            // padded K stride (bf16) for bond GEMM panel
#define N_WT (WCOLS * WSTR) // 28288
#define PSTR 72             // atomproj panel K stride (bf16), 16B-aligned cols
#define PCOLS 144           // 64 w1 + 64 w2 + fw1 + fw2 + pad
#define PSZ (PCOLS * PSTR)  // 10368 shorts per (hi|lo) panel

#define NBLK 768            // conv_all grid: 3 blocks/CU, all co-resident
#define NGRP 8
#define GSZ (NBLK / NGRP)   // 96 arrivals per group line

#define N_EMB (BB * NN * FF)        // 1048576
#define N_FOLD 192
#define N_WPROJ (3 * PSZ)           // 31104
#define N_BAR (6 * 9 * 32)          // 6 barriers x (8 group + 1 root) x 32-int lines
#define N_PREP (N_EMB + N_FOLD + N_WT + N_WPROJ + N_BAR)

typedef __attribute__((ext_vector_type(8))) short bf16x8;
typedef __attribute__((ext_vector_type(4))) float f32x4;

static __device__ __forceinline__ unsigned short f2bf(float f) {
    union { float f; unsigned u; } c; c.f = f;
    unsigned r = c.u + 0x7fff + ((c.u >> 16) & 1);   // RNE
    return (unsigned short)(r >> 16);
}
static __device__ __forceinline__ float bf2f(unsigned short s) {
    union { unsigned u; float f; } c; c.u = ((unsigned)s) << 16;
    return c.f;
}
static __device__ __forceinline__ bf16x8 pack_bf16x8(float4 a, float4 b) {
    union { unsigned u[4]; bf16x8 v; } r;
    r.u[0] = (unsigned)f2bf(a.x) | ((unsigned)f2bf(a.y) << 16);
    r.u[1] = (unsigned)f2bf(a.z) | ((unsigned)f2bf(a.w) << 16);
    r.u[2] = (unsigned)f2bf(b.x) | ((unsigned)f2bf(b.y) << 16);
    r.u[3] = (unsigned)f2bf(b.z) | ((unsigned)f2bf(b.w) << 16);
    return r.v;
}
static __device__ __forceinline__ float4 residual4(float4 v) {
    float4 r;
    r.x = v.x - bf2f(f2bf(v.x));
    r.y = v.y - bf2f(f2bf(v.y));
    r.z = v.z - bf2f(f2bf(v.z));
    r.w = v.w - bf2f(f2bf(v.w));
    return r;
}

// Hierarchical grid barrier. Arrivals fan into 8 per-group cachelines
// (grp = blockIdx&7 tracks the XCD round-robin), the 8 group-leaders bump a
// root line, everyone spins on root with backoff. Counters zeroed by prep
// each launch (graph-replay safe). Release/acquire via __threadfence().
static __device__ __forceinline__ void grid_barrier(int* bar, int idx, int grp) {
    __syncthreads();
    if (threadIdx.x == 0) {
        __threadfence();
        int* gcnt = bar + (idx * 9 + grp) * 32;
        int* root = bar + (idx * 9 + 8) * 32;
        int old = __hip_atomic_fetch_add(gcnt, 1, __ATOMIC_RELAXED, __HIP_MEMORY_SCOPE_AGENT);
        if (old == GSZ - 1)
            __hip_atomic_fetch_add(root, 1, __ATOMIC_RELAXED, __HIP_MEMORY_SCOPE_AGENT);
        while (__hip_atomic_load(root, __ATOMIC_RELAXED, __HIP_MEMORY_SCOPE_AGENT) < NGRP)
            __builtin_amdgcn_s_sleep(4);
        __threadfence();
    }
    __syncthreads();
}

// ---- all preprocessing in one launch ---------------------------------------
// [0,N_EMB): embedding gather -> x
// [+N_FOLD): BN-a folded core bias cbp
// [+N_WT): bond-GEMM panel wT (R3 format: permuted cols, WSTR=136, no swizzle)
// [+N_WPROJ): atomproj hi/lo split-bf16 panels (PSTR=72)
// [+N_BAR): zero the grid-barrier counters
__global__ void prep_all(const int* __restrict__ at, const float* __restrict__ emb,
                         const float* __restrict__ cw, const float* __restrict__ cb,
                         const float* __restrict__ fw, const float* __restrict__ g,
                         const float* __restrict__ bab,
                         float* __restrict__ x, float* __restrict__ cbp,
                         unsigned short* __restrict__ wT,
                         unsigned short* __restrict__ wproj,
                         int* __restrict__ bar) {
    int i = blockIdx.x * 256 + threadIdx.x;
    if (i < N_EMB) {
        x[i] = emb[at[i >> 6] * FF + (i & 63)];
        return;
    }
    i -= N_EMB;
    if (i < N_FOLD) {
        int f = i & 63, l = i >> 6;
        float gs = g[l * 64 + f] * S_BN;
        cbp[i] = cb[l * 64 + f] * gs + bab[l * 64 + f];
        return;
    }
    i -= N_FOLD;
    if (i < N_WT) {
        int col = i / WSTR, k = i % WSTR;
        float v = 0.f;
        if (k < 128) {
            if (col < 192) {
                int l = col >> 6, p = col & 63;
                int f = ((p & 15) << 2) | (p >> 4);       // 4*m + tt
                v = cw[(l * 256 + 128 + k) * 64 + f] * g[l * 64 + f] * S_BN;
            } else if (col < 195) {
                int l = col - 192;
                v = fw[l * 256 + 128 + k];
            }
        }
        wT[i] = f2bf(v);
        return;
    }
    i -= N_WT;
    if (i < N_WPROJ) {
        int l = i / PSZ;
        int rem = i - l * PSZ;
        int col = rem / PSTR, k = rem - col * PSTR;
        float v = 0.f;
        if (k < 64) {
            if (col < 64)
                v = cw[(l * 256 + k) * 64 + col] * g[l * 64 + col] * S_BN;
            else if (col < 128)
                v = cw[(l * 256 + 64 + k) * 64 + (col - 64)] * g[l * 64 + (col - 64)] * S_BN;
            else if (col == 128)
                v = fw[l * 256 + k];
            else if (col == 129)
                v = fw[l * 256 + 64 + k];
        }
        unsigned short hi = f2bf(v);
        wproj[(size_t)l * 2 * PSZ + col * PSTR + k] = hi;
        wproj[(size_t)l * 2 * PSZ + PSZ + col * PSTR + k] = f2bf(v - bf2f(hi));
        return;
    }
    i -= N_WPROJ;
    if (i < N_BAR) bar[i] = 0;
}

// ---- one-shot bf16 MFMA GEMM (R3-proven body, verbatim) --------------------
// A = bond (196608 x 128, fp32 -> bf16 in registers), B = wT (128 x 208)
// 512 blocks x 6 iters x 64 rows; panel staged once; (256,2) -> VGPR 128.
__global__ __launch_bounds__(256, 2) void gemm_bond(
    const float* __restrict__ bond, const unsigned short* __restrict__ wT,
    unsigned short* __restrict__ core, float* __restrict__ filt) {
    __shared__ unsigned short bsh[WCOLS * WSTR];  // 56576 B weights
    int tid = threadIdx.x;
    int wv = tid >> 6, lane = tid & 63;
    int m = lane & 15, quad = lane >> 4;

    // stage weights ONCE (3536 float4)
    const float4* wsrc = (const float4*)wT;
    float4* wdst = (float4*)bsh;
    #pragma unroll
    for (int i = 0; i < 14; i++) {
        int idx = tid + 256 * i;
        if (idx < (WCOLS * WSTR * 2) / 16) wdst[idx] = wsrc[idx];
    }
    __syncthreads();

    #pragma unroll 1
    for (int it = 0; it < 6; it++) {
        int row0 = blockIdx.x * 384 + it * 64;
        const float* abase = bond + (size_t)(row0 + wv * 16 + m) * BFE + quad * 8;

        bf16x8 af[4];
        #pragma unroll
        for (int c = 0; c < 4; c++) {
            float4 v0 = *(const float4*)(abase + c * 32);
            float4 v1 = *(const float4*)(abase + c * 32 + 4);
            af[c] = pack_bf16x8(v0, v1);
        }

        f32x4 acc[13];
        #pragma unroll
        for (int t = 0; t < 13; t++) acc[t] = (f32x4){0.f, 0.f, 0.f, 0.f};

        #pragma unroll
        for (int c = 0; c < 4; c++) {
            bf16x8 a = af[c];
            #pragma unroll
            for (int t = 0; t < 13; t++) {
                bf16x8 bfv = *(const bf16x8*)&bsh[(t * 16 + m) * WSTR + c * 32 + quad * 8];
                acc[t] = __builtin_amdgcn_mfma_f32_16x16x32_bf16(a, bfv, acc[t], 0, 0, 0);
            }
        }

        int crow = row0 + wv * 16 + quad * 4;
        #pragma unroll
        for (int l = 0; l < 3; l++) {
            #pragma unroll
            for (int r = 0; r < 4; r++) {
                ushort4 h;
                h.x = f2bf(acc[l * 4 + 0][r]);
                h.y = f2bf(acc[l * 4 + 1][r]);
                h.z = f2bf(acc[l * 4 + 2][r]);
                h.w = f2bf(acc[l * 4 + 3][r]);
                *(ushort4*)&core[((size_t)l * RT + crow + r) * 64 + 4 * m] = h;
            }
        }
        if (m < 3) {
            #pragma unroll
            for (int r = 0; r < 4; r++)
                filt[(size_t)m * RT + crow + r] = acc[12][r];
        }
    }
}

// ---- fused conv kernel: 3x (atomproj phase -> layer_ep phase) + final -----
// grid 768 x 256 (3 blocks/CU, ALL co-resident), LDS 42496 B. R7-proven body;
// only the barrier implementation changed.
__global__ __launch_bounds__(256, 3) void conv_all(
    float* __restrict__ xA, float* __restrict__ xB,
    const unsigned short* __restrict__ wproj, const float* __restrict__ cbp,
    const float* __restrict__ fb,
    const unsigned short* __restrict__ core, const float* __restrict__ filt,
    const int* __restrict__ nbr,
    float* __restrict__ ys, float* __restrict__ yn,
    float* __restrict__ fs, float* __restrict__ fn,
    const float* __restrict__ bbg, const float* __restrict__ bbb,
    const int* __restrict__ tidx, const float* __restrict__ dw,
    const float* __restrict__ db, float* __restrict__ out,
    int* __restrict__ bar) {
    __shared__ unsigned short panel[2 * PSZ];   // 41472 B (reused for dw)
    __shared__ float xsf[4][64];
    int tid = threadIdx.x, wv = tid >> 6, lane = tid & 63;
    int m = lane & 15, quad = lane >> 4;
    int gw = blockIdx.x * 4 + wv;                // 0..3071
    int grp = blockIdx.x & 7;
    int baridx = 0;

    float* xin = xA;
    float* xout = xB;

    #pragma unroll 1
    for (int l = 0; l < 3; l++) {
        // ---- stage atomproj panel for layer l (2592 float4) ----
        const float4* psrc = (const float4*)(wproj + (size_t)l * 2 * PSZ);
        float4* pdst = (float4*)panel;
        #pragma unroll
        for (int i = 0; i < 11; i++) {
            int idx = tid + 256 * i;
            if (idx < (2 * PSZ * 2) / 16) pdst[idx] = psrc[idx];
        }
        __syncthreads();

        // ---- phase A: atomproj (9216 units = 1024 fragments x 9 tiles) ----
        const float* cbp_l = cbp + l * 64;
        float fbv = fb[l];
        #pragma unroll 1
        for (int j = 0; j < 3; j++) {
            int u = gw + 3072 * j;                // exact cover of [0,9216)
            int f = u / 9, t = u - f * 9;
            const float* xb = xin + ((size_t)f * 16 + m) * 64 + quad * 8;
            bf16x8 ahi[2], alo[2];
            #pragma unroll
            for (int c = 0; c < 2; c++) {
                float4 v0 = *(const float4*)(xb + c * 32);
                float4 v1 = *(const float4*)(xb + c * 32 + 4);
                ahi[c] = pack_bf16x8(v0, v1);
                alo[c] = pack_bf16x8(residual4(v0), residual4(v1));
            }
            f32x4 acc = (f32x4){0.f, 0.f, 0.f, 0.f};
            #pragma unroll
            for (int c = 0; c < 2; c++) {
                int off = (t * 16 + m) * PSTR + c * 32 + quad * 8;
                bf16x8 bh = *(const bf16x8*)&panel[off];
                bf16x8 bl = *(const bf16x8*)&panel[PSZ + off];
                acc = __builtin_amdgcn_mfma_f32_16x16x32_bf16(ahi[c], bh, acc, 0, 0, 0);
                acc = __builtin_amdgcn_mfma_f32_16x16x32_bf16(alo[c], bh, acc, 0, 0, 0);
                acc = __builtin_amdgcn_mfma_f32_16x16x32_bf16(ahi[c], bl, acc, 0, 0, 0);
            }
            int crow = f * 16 + quad * 4;
            if (t < 4) {
                float bias = cbp_l[t * 16 + m];
                #pragma unroll
                for (int r = 0; r < 4; r++)
                    ys[(size_t)(crow + r) * 64 + t * 16 + m] = acc[r] + bias;
            } else if (t < 8) {
                #pragma unroll
                for (int r = 0; r < 4; r++)
                    yn[(size_t)(crow + r) * 64 + (t - 4) * 16 + m] = acc[r];
            } else {
                if (m == 0) {
                    #pragma unroll
                    for (int r = 0; r < 4; r++) fs[crow + r] = acc[r] + fbv;
                }
                if (m == 1) {
                    #pragma unroll
                    for (int r = 0; r < 4; r++) fn[crow + r] = acc[r];
                }
            }
        }
        grid_barrier(bar, baridx++, grp);

        // ---- phase B: softmax + weighted mean + BN-b + residual ----
        const unsigned short* core_l = core + (size_t)l * RT * 64;
        const float* filt_l = filt + (size_t)l * RT;
        float bg = bbg[l * 64 + lane], bbv = bbb[l * 64 + lane];
        #pragma unroll 1
        for (int k = 0; k < 6; k++) {
            int row = gw + 3072 * k;              // 16384 rows grid-strided
            if (row >= BB * NN) break;
            int base = (row >> 10) * NN;
            size_t rb = (size_t)row * MM;

            int jv[MM]; float fltv[MM], corev[MM];
            #pragma unroll
            for (int mm = 0; mm < MM; mm++) jv[mm] = nbr[rb + mm];
            float fsv = fs[row], ysv = ys[(size_t)row * 64 + lane];
            #pragma unroll
            for (int mm = 0; mm < MM; mm++)
                fltv[mm] = filt_l[rb + mm] + fsv + fn[base + jv[mm]];
            #pragma unroll
            for (int mm = 0; mm < MM; mm++)
                corev[mm] = bf2f(core_l[(rb + mm) * 64 + lane]) + ysv
                          + yn[(size_t)(base + jv[mm]) * 64 + lane];
            float fmax = -1e30f;
            #pragma unroll
            for (int mm = 0; mm < MM; mm++) fmax = fmaxf(fmax, fltv[mm]);
            float fsum = 0.f;
            #pragma unroll
            for (int mm = 0; mm < MM; mm++) { fltv[mm] = __expf(fltv[mm] - fmax); fsum += fltv[mm]; }
            float inv = 1.f / (12.f * fsum);
            float summed = 0.f;
            #pragma unroll
            for (int mm = 0; mm < MM; mm++) summed += fltv[mm] * fmaxf(corev[mm], 0.f);
            summed *= inv;
            float o = xin[(size_t)row * 64 + lane] + bg * (summed * S_BN) + bbv;
            xout[(size_t)row * 64 + lane] = fmaxf(o, 0.f);
        }
        grid_barrier(bar, baridx++, grp);
        float* tswap = xin; xin = xout; xout = tswap;
    }

    // ---- final: pooling gather + dense + relu (blocks 0..255) ----
    if (blockIdx.x < 256) {
        float* dwsh = (float*)panel;   // 16 KB, panel is dead now
        const float4* src = (const float4*)dw;
        #pragma unroll
        for (int i = 0; i < 4; i++) ((float4*)dwsh)[tid + 256 * i] = src[tid + 256 * i];
        int row = blockIdx.x * 4 + wv;
        int b = row >> 6;
        int t = tidx[row];
        float xv = xin[((size_t)b * NN + t) * 64 + lane];
        xsf[wv][lane] = fmaxf(xv, 0.f);
        __syncthreads();
        float a = db[lane];
        #pragma unroll 16
        for (int k = 0; k < 64; k++) a += xsf[wv][k] * dwsh[k * 64 + lane];
        out[row * 64 + lane] = fmaxf(a, 0.f);
    }
}

extern "C" void kernel_launch(void* const* d_in, const int* in_sizes, int n_in,
                              void* d_out, int out_size, void* d_ws, size_t ws_size,
                              hipStream_t stream) {
    const int*   at   = (const int*)d_in[0];
    const float* bond = (const float*)d_in[1];
    const int*   nbr  = (const int*)d_in[2];
    const int*   tgt  = (const int*)d_in[3];
    const float* emb  = (const float*)d_in[4];
    const float* cw   = (const float*)d_in[5];
    const float* cb   = (const float*)d_in[6];
    const float* fw   = (const float*)d_in[7];
    const float* fb   = (const float*)d_in[8];
    const float* bag  = (const float*)d_in[9];
    const float* bab  = (const float*)d_in[10];
    const float* bbg  = (const float*)d_in[11];
    const float* bbb  = (const float*)d_in[12];
    const float* dw   = (const float*)d_in[13];
    const float* db   = (const float*)d_in[14];

    float* ws   = (float*)d_ws;
    float* xA   = ws;
    float* xB   = xA + (size_t)BB * NN * FF;          // 1,048,576 each
    float* cwp  = xB + (size_t)BB * NN * FF;          // 49,152 (holds wproj)
    float* cbp  = cwp + 3 * 256 * 64;                 // 192
    float* ys   = cbp + 192;                          // 1,048,576
    float* yn   = ys + (size_t)BB * NN * FF;          // 1,048,576
    float* fs   = yn + (size_t)BB * NN * FF;          // 16,384
    float* fn   = fs + (size_t)BB * NN;               // 16,384
    float* filt = fn + (size_t)BB * NN;               // 3*196608 fp32
    unsigned short* wT   = (unsigned short*)(filt + 3 * (size_t)RT);  // 28,288 bf16
    unsigned short* core = wT + N_WT;                 // 3*196608*64 bf16 (~75.5 MB)
    int* bar = (int*)(core + 3 * (size_t)RT * 64);    // 1728 ints
    unsigned short* wproj = (unsigned short*)cwp;     // 62,208 shorts (fits)
    float* outp = (float*)d_out;

    prep_all<<<(N_PREP + 255) / 256, 256, 0, stream>>>(
        at, emb, cw, cb, fw, bag, bab, xA, cbp, wT, wproj, bar);
    gemm_bond<<<512, 256, 0, stream>>>(bond, wT, core, filt);
    conv_all<<<NBLK, 256, 0, stream>>>(
        xA, xB, wproj, cbp, fb, core, filt, nbr,
        ys, yn, fs, fn, bbg, bbb, tgt, dw, db, outp, bar);
}

// Round 10
// 292.119 us; speedup vs baseline: 1.6436x; 1.6436x over previous
//
#include <hip/hip_runtime.h>
#include <hip/hip_bf16.h>

// CGCNN: B=16, N=1024, M=12, F=64, BF=128, 3 conv layers.
// bond is layer-invariant -> ONE bf16 MFMA GEMM produces core+filt for all
// 3 layers. Per-layer: atomproj_mfma + layer_ep (separate launches).
//
// Ledger: R3 split 280us (gemm 80 @ (256,2)=VGPR128 clean). R7/R9 fused conv
//   with SW grid barriers: correct but barriers cost 90us/40us each -> fusion
//   CLOSED (launch boundaries are cheaper than cross-XCD barrier traffic).
// R8: swizzled 53248B panel + grid 768 passed (absmax OK) but
//   __launch_bounds__(256,3) -> allocator targeted 84 VGPR -> spill, 157us.
// R10: R8 with ONE change: gemm launch bounds (256,2) -> 128 VGPR (proven
//   clean codegen). HW still fits 3 blocks/CU: LDS 3x53248=159744<=163840,
//   VGPR 3 waves/SIMD x 128 = 384 <= 512. 12 waves/CU on a latency-bound
//   kernel -> predict gemm ~55us.

#define BB 16
#define NN 1024
#define MM 12
#define FF 64
#define BFE 128
#define RT (BB * NN * MM)   // 196608 bond rows
#define S_BN 0.99950037f    // 1/sqrt(1+1e-3)
#define WCOLS 208           // 192 core cols (3 layers x 64) + 3 filt + 13 pad
#define NWT (WCOLS * 128)   // 26624 bf16, XOR-swizzled, no pad
#define PSTR 72             // atomproj panel K stride (bf16), 16B-aligned cols
#define PCOLS 144           // 64 w1 + 64 w2 + fw1 + fw2 + pad
#define PSZ (PCOLS * PSTR)  // 10368 shorts per (hi|lo) panel

#define N_EMB (BB * NN * FF)        // 1048576
#define N_FOLD 192
#define N_WPROJ (3 * PSZ)           // 31104
#define N_PREP (N_EMB + N_FOLD + NWT + N_WPROJ)

typedef __attribute__((ext_vector_type(8))) short bf16x8;
typedef __attribute__((ext_vector_type(4))) float f32x4;

static __device__ __forceinline__ unsigned short f2bf(float f) {
    union { float f; unsigned u; } c; c.f = f;
    unsigned r = c.u + 0x7fff + ((c.u >> 16) & 1);   // RNE
    return (unsigned short)(r >> 16);
}
static __device__ __forceinline__ float bf2f(unsigned short s) {
    union { unsigned u; float f; } c; c.u = ((unsigned)s) << 16;
    return c.f;
}
static __device__ __forceinline__ bf16x8 pack_bf16x8(float4 a, float4 b) {
    union { unsigned u[4]; bf16x8 v; } r;
    r.u[0] = (unsigned)f2bf(a.x) | ((unsigned)f2bf(a.y) << 16);
    r.u[1] = (unsigned)f2bf(a.z) | ((unsigned)f2bf(a.w) << 16);
    r.u[2] = (unsigned)f2bf(b.x) | ((unsigned)f2bf(b.y) << 16);
    r.u[3] = (unsigned)f2bf(b.z) | ((unsigned)f2bf(b.w) << 16);
    return r.v;
}
static __device__ __forceinline__ float4 residual4(float4 v) {
    float4 r;
    r.x = v.x - bf2f(f2bf(v.x));
    r.y = v.y - bf2f(f2bf(v.y));
    r.z = v.z - bf2f(f2bf(v.z));
    r.w = v.w - bf2f(f2bf(v.w));
    return r;
}

// ---- all preprocessing in one launch ---------------------------------------
// [0,N_EMB): embedding gather -> x
// [+N_FOLD): BN-a folded core bias cbp
// [+NWT): bond-GEMM panel wT: permuted cols, XOR-swizzled (k ^ (col&7)<<3)
// [+N_WPROJ): atomproj hi/lo split-bf16 panels (PSTR=72)
__global__ void prep_all(const int* __restrict__ at, const float* __restrict__ emb,
                         const float* __restrict__ cw, const float* __restrict__ cb,
                         const float* __restrict__ fw, const float* __restrict__ g,
                         const float* __restrict__ bab,
                         float* __restrict__ x, float* __restrict__ cbp,
                         unsigned short* __restrict__ wT,
                         unsigned short* __restrict__ wproj) {
    int i = blockIdx.x * 256 + threadIdx.x;
    if (i < N_EMB) {
        x[i] = emb[at[i >> 6] * FF + (i & 63)];
        return;
    }
    i -= N_EMB;
    if (i < N_FOLD) {
        int f = i & 63, l = i >> 6;
        float gs = g[l * 64 + f] * S_BN;
        cbp[i] = cb[l * 64 + f] * gs + bab[l * 64 + f];
        return;
    }
    i -= N_FOLD;
    if (i < NWT) {
        int col = i >> 7, k = i & 127;
        float v = 0.f;
        if (col < 192) {
            int l = col >> 6, p = col & 63;
            int f = ((p & 15) << 2) | (p >> 4);       // 4*m + tt
            v = cw[(l * 256 + 128 + k) * 64 + f] * g[l * 64 + f] * S_BN;
        } else if (col < 195) {
            int l = col - 192;
            v = fw[l * 256 + 128 + k];
        }
        wT[i ^ ((col & 7) << 3)] = f2bf(v);           // write-side swizzle
        return;
    }
    i -= NWT;
    if (i < N_WPROJ) {
        int l = i / PSZ;
        int rem = i - l * PSZ;
        int col = rem / PSTR, k = rem - col * PSTR;
        float v = 0.f;
        if (k < 64) {
            if (col < 64)
                v = cw[(l * 256 + k) * 64 + col] * g[l * 64 + col] * S_BN;
            else if (col < 128)
                v = cw[(l * 256 + 64 + k) * 64 + (col - 64)] * g[l * 64 + (col - 64)] * S_BN;
            else if (col == 128)
                v = fw[l * 256 + k];
            else if (col == 129)
                v = fw[l * 256 + 64 + k];
        }
        unsigned short hi = f2bf(v);
        wproj[(size_t)l * 2 * PSZ + col * PSTR + k] = hi;
        wproj[(size_t)l * 2 * PSZ + PSZ + col * PSTR + k] = f2bf(v - bf2f(hi));
    }
}

// ---- one-shot bf16 MFMA GEMM: core_{0,1,2} (bf16) + filt_{0,1,2} (fp32) ----
// A = bond (196608 x 128, fp32 -> bf16 in registers), B = wT (128 x 208)
// 768 blocks x 4 iters x 64 rows; panel staged once. __launch_bounds__(256,2)
// = 128-VGPR codegen (proven); HW fits 3 blocks/CU by LDS/VGPR arithmetic.
__global__ __launch_bounds__(256, 2) void gemm_bond(
    const float* __restrict__ bond, const unsigned short* __restrict__ wT,
    unsigned short* __restrict__ core, float* __restrict__ filt) {
    __shared__ unsigned short bsh[NWT];   // 53248 B, swizzled layout
    int tid = threadIdx.x;
    int wv = tid >> 6, lane = tid & 63;
    int m = lane & 15, quad = lane >> 4;

    // stage panel ONCE: 3328 float4, 13/thread exact
    const float4* wsrc = (const float4*)wT;
    float4* wdst = (float4*)bsh;
    #pragma unroll
    for (int i = 0; i < 13; i++) wdst[tid + 256 * i] = wsrc[tid + 256 * i];
    __syncthreads();

    int swz = (m & 7) << 3;               // element-index XOR (16B-aligned)

    #pragma unroll 1
    for (int it = 0; it < 4; it++) {
        int row0 = blockIdx.x * 256 + it * 64;
        const float* abase = bond + (size_t)(row0 + wv * 16 + m) * BFE + quad * 8;

        bf16x8 af[4];
        #pragma unroll
        for (int c = 0; c < 4; c++) {
            float4 v0 = *(const float4*)(abase + c * 32);
            float4 v1 = *(const float4*)(abase + c * 32 + 4);
            af[c] = pack_bf16x8(v0, v1);
        }

        f32x4 acc[13];
        #pragma unroll
        for (int t = 0; t < 13; t++) acc[t] = (f32x4){0.f, 0.f, 0.f, 0.f};

        #pragma unroll
        for (int c = 0; c < 4; c++) {
            bf16x8 a = af[c];
            #pragma unroll
            for (int t = 0; t < 13; t++) {
                int e = (t * 2048 + m * 128 + c * 32 + quad * 8) ^ swz;
                bf16x8 bfv = *(const bf16x8*)&bsh[e];
                acc[t] = __builtin_amdgcn_mfma_f32_16x16x32_bf16(a, bfv, acc[t], 0, 0, 0);
            }
        }

        int crow = row0 + wv * 16 + quad * 4;
        #pragma unroll
        for (int l = 0; l < 3; l++) {
            #pragma unroll
            for (int r = 0; r < 4; r++) {
                ushort4 h;
                h.x = f2bf(acc[l * 4 + 0][r]);
                h.y = f2bf(acc[l * 4 + 1][r]);
                h.z = f2bf(acc[l * 4 + 2][r]);
                h.w = f2bf(acc[l * 4 + 3][r]);
                *(ushort4*)&core[((size_t)l * RT + crow + r) * 64 + 4 * m] = h;
            }
        }
        if (m < 3) {
            #pragma unroll
            for (int r = 0; r < 4; r++)
                filt[(size_t)m * RT + crow + r] = acc[12][r];
        }
    }
}

// ---- per-atom projections via MFMA (hi/lo split-bf16, ~f32 accuracy) -------
// C = x (16384x64) @ panel (64x144): cols 0..63 ys (+bias), 64..127 yn,
// 128 fs-proj (+fb), 129 fn-proj. acc = Ahi*Bhi + Alo*Bhi + Ahi*Blo.
__global__ __launch_bounds__(256) void atomproj_mfma(
    const float* __restrict__ x, const unsigned short* __restrict__ wproj_l,
    const float* __restrict__ cbp_l, const float* __restrict__ fb_l,
    float* __restrict__ ys, float* __restrict__ yn,
    float* __restrict__ fs, float* __restrict__ fn) {
    __shared__ unsigned short psh[2 * PSZ];   // 41472 B: hi panel then lo panel
    int tid = threadIdx.x, w = tid >> 6, lane = tid & 63;
    int m = lane & 15, quad = lane >> 4;

    const float4* src = (const float4*)wproj_l;
    float4* dst = (float4*)psh;
    #pragma unroll
    for (int i = 0; i < 11; i++) {
        int idx = tid + 256 * i;
        if (idx < (2 * PSZ * 2) / 16) dst[idx] = src[idx];
    }
    __syncthreads();

    int row = blockIdx.x * 64 + w * 16 + m;
    const float* xb = x + (size_t)row * 64 + quad * 8;
    bf16x8 ahi[2], alo[2];
    #pragma unroll
    for (int c = 0; c < 2; c++) {
        float4 v0 = *(const float4*)(xb + c * 32);
        float4 v1 = *(const float4*)(xb + c * 32 + 4);
        ahi[c] = pack_bf16x8(v0, v1);
        alo[c] = pack_bf16x8(residual4(v0), residual4(v1));
    }

    f32x4 acc[9];
    #pragma unroll
    for (int t = 0; t < 9; t++) acc[t] = (f32x4){0.f, 0.f, 0.f, 0.f};

    #pragma unroll
    for (int c = 0; c < 2; c++) {
        #pragma unroll
        for (int t = 0; t < 9; t++) {
            int off = (t * 16 + m) * PSTR + c * 32 + quad * 8;
            bf16x8 bh = *(const bf16x8*)&psh[off];
            bf16x8 bl = *(const bf16x8*)&psh[PSZ + off];
            acc[t] = __builtin_amdgcn_mfma_f32_16x16x32_bf16(ahi[c], bh, acc[t], 0, 0, 0);
            acc[t] = __builtin_amdgcn_mfma_f32_16x16x32_bf16(alo[c], bh, acc[t], 0, 0, 0);
            acc[t] = __builtin_amdgcn_mfma_f32_16x16x32_bf16(ahi[c], bl, acc[t], 0, 0, 0);
        }
    }

    int crow = blockIdx.x * 64 + w * 16 + quad * 4;
    #pragma unroll
    for (int t = 0; t < 4; t++) {
        float bias = cbp_l[t * 16 + m];
        #pragma unroll
        for (int r = 0; r < 4; r++)
            ys[(size_t)(crow + r) * 64 + t * 16 + m] = acc[t][r] + bias;
    }
    #pragma unroll
    for (int t = 4; t < 8; t++) {
        #pragma unroll
        for (int r = 0; r < 4; r++)
            yn[(size_t)(crow + r) * 64 + (t - 4) * 16 + m] = acc[t][r];
    }
    if (m == 0) {
        float fbv = fb_l[0];
        #pragma unroll
        for (int r = 0; r < 4; r++) fs[crow + r] = acc[8][r] + fbv;
    }
    if (m == 1) {
        #pragma unroll
        for (int r = 0; r < 4; r++) fn[crow + r] = acc[8][r];
    }
}

// ---- per-layer epilogue: softmax + weighted mean + BN-b + residual ---------
// XCD swizzle: blocks with bid%8==x (dispatched to XCD x) take contiguous
// row range [x*2048,(x+1)*2048) = 2 batches -> gathers are XCD-L2-local.
__global__ __launch_bounds__(256) void layer_ep(
    const float* __restrict__ x, const unsigned short* __restrict__ core_l,
    const float* __restrict__ filt_l, const int* __restrict__ nbr,
    const float* __restrict__ ys, const float* __restrict__ yn,
    const float* __restrict__ fs, const float* __restrict__ fn,
    const float* __restrict__ bbg, const float* __restrict__ bbb,
    float* __restrict__ xout) {
    int tid = threadIdx.x, w = tid >> 6, lane = tid & 63;
    int sb = (blockIdx.x & 7) * 512 + (blockIdx.x >> 3);   // bijective, grid 4096
    int row = sb * 4 + w;
    int base = (row >> 10) * NN;
    size_t rb = (size_t)row * MM;

    int jv[MM]; float fltv[MM], corev[MM];
    #pragma unroll
    for (int mm = 0; mm < MM; mm++) jv[mm] = nbr[rb + mm];
    float fsv = fs[row], ysv = ys[(size_t)row * 64 + lane];
    #pragma unroll
    for (int mm = 0; mm < MM; mm++)
        fltv[mm] = filt_l[rb + mm] + fsv + fn[base + jv[mm]];
    #pragma unroll
    for (int mm = 0; mm < MM; mm++)
        corev[mm] = bf2f(core_l[(rb + mm) * 64 + lane]) + ysv
                  + yn[(size_t)(base + jv[mm]) * 64 + lane];
    float fmax = -1e30f;
    #pragma unroll
    for (int mm = 0; mm < MM; mm++) fmax = fmaxf(fmax, fltv[mm]);
    float fsum = 0.f;
    #pragma unroll
    for (int mm = 0; mm < MM; mm++) { fltv[mm] = __expf(fltv[mm] - fmax); fsum += fltv[mm]; }
    float inv = 1.f / (12.f * fsum);
    float summed = 0.f;
    #pragma unroll
    for (int mm = 0; mm < MM; mm++) summed += fltv[mm] * fmaxf(corev[mm], 0.f);
    summed *= inv;
    float o = x[(size_t)row * 64 + lane] + bbg[lane] * (summed * S_BN) + bbb[lane];
    xout[(size_t)row * 64 + lane] = fmaxf(o, 0.f);
}

// ---- pooling gather + dense + relu ----------------------------------------
__global__ __launch_bounds__(256) void final_k(
    const float* __restrict__ x, const int* __restrict__ tidx,
    const float* __restrict__ dw, const float* __restrict__ db,
    float* __restrict__ out) {
    __shared__ float xs[4][64];
    __shared__ float wsh[64 * 64];
    int tid = threadIdx.x;
    int w = tid >> 6, lane = tid & 63;
    const float4* src = (const float4*)dw;
    float4* dst = (float4*)wsh;
    #pragma unroll
    for (int i = 0; i < 4; i++) dst[tid + 256 * i] = src[tid + 256 * i];
    int row = blockIdx.x * 4 + w;        // b*64 + i
    int b = row >> 6;
    int t = tidx[row];
    float xv = x[((size_t)b * NN + t) * 64 + lane];
    xs[w][lane] = fmaxf(xv, 0.f);
    __syncthreads();
    float a = db[lane];
    #pragma unroll 16
    for (int k = 0; k < 64; k++) a += xs[w][k] * wsh[k * 64 + lane];
    out[row * 64 + lane] = fmaxf(a, 0.f);
}

extern "C" void kernel_launch(void* const* d_in, const int* in_sizes, int n_in,
                              void* d_out, int out_size, void* d_ws, size_t ws_size,
                              hipStream_t stream) {
    const int*   at   = (const int*)d_in[0];
    const float* bond = (const float*)d_in[1];
    const int*   nbr  = (const int*)d_in[2];
    const int*   tgt  = (const int*)d_in[3];
    const float* emb  = (const float*)d_in[4];
    const float* cw   = (const float*)d_in[5];
    const float* cb   = (const float*)d_in[6];
    const float* fw   = (const float*)d_in[7];
    const float* fb   = (const float*)d_in[8];
    const float* bag  = (const float*)d_in[9];
    const float* bab  = (const float*)d_in[10];
    const float* bbg  = (const float*)d_in[11];
    const float* bbb  = (const float*)d_in[12];
    const float* dw   = (const float*)d_in[13];
    const float* db   = (const float*)d_in[14];

    float* ws   = (float*)d_ws;
    float* xA   = ws;
    float* xB   = xA + (size_t)BB * NN * FF;          // 1,048,576 each
    float* cwp  = xB + (size_t)BB * NN * FF;          // 49,152 (holds wproj)
    float* cbp  = cwp + 3 * 256 * 64;                 // 192
    float* ys   = cbp + 192;                          // 1,048,576
    float* yn   = ys + (size_t)BB * NN * FF;          // 1,048,576
    float* fs   = yn + (size_t)BB * NN * FF;          // 16,384
    float* fn   = fs + (size_t)BB * NN;               // 16,384
    float* filt = fn + (size_t)BB * NN;               // 3*196608 fp32
    unsigned short* wT   = (unsigned short*)(filt + 3 * (size_t)RT);  // 26,624 bf16
    unsigned short* core = wT + NWT;                  // 3*196608*64 bf16 (~75.5 MB)
    unsigned short* wproj = (unsigned short*)cwp;     // 62,208 shorts (fits)
    // total ~95 MB

    prep_all<<<(N_PREP + 255) / 256, 256, 0, stream>>>(
        at, emb, cw, cb, fw, bag, bab, xA, cbp, wT, wproj);
    gemm_bond<<<768, 256, 0, stream>>>(bond, wT, core, filt);

    float* xin = xA;
    float* xout = xB;
    for (int l = 0; l < 3; l++) {
        atomproj_mfma<<<BB * NN / 64, 256, 0, stream>>>(
            xin, wproj + (size_t)l * 2 * PSZ, cbp + l * 64, fb + l,
            ys, yn, fs, fn);
        layer_ep<<<BB * NN / 4, 256, 0, stream>>>(
            xin, core + (size_t)l * RT * 64, filt + (size_t)l * RT, nbr,
            ys, yn, fs, fn, bbg + l * 64, bbb + l * 64, xout);
        float* t = xin; xin = xout; xout = t;
    }

    final_k<<<BB * 64 / 4, 256, 0, stream>>>(xin, tgt, dw, db, (float*)d_out);
}

// Round 11
// 280.422 us; speedup vs baseline: 1.7122x; 1.0417x over previous
//
#include <hip/hip_runtime.h>
#include <hip/hip_bf16.h>

// CGCNN: B=16, N=1024, M=12, F=64, BF=128, 3 conv layers.
// bond is layer-invariant -> ONE bf16 MFMA GEMM produces core+filt for all
// 3 layers. Per-layer: atomproj_mfma + layer_ep (separate launches).
//
// Ledger: R3 split 280us (gemm 80: padded WSTR=136 panel, 512 blocks,
//   (256,2)=VGPR128 — proven best config; swizzled/3-per-CU tried 3x, always
//   worse). Fusion CLOSED (R7/R9: SW grid barriers 40-90us each).
// R11: R3 gemm config + two targeted fixes:
//   (a) panel staged via __builtin_amdgcn_global_load_lds width=16 (kills the
//       14-float4 prologue batch = the +16MB scratch WRITE excess);
//   (b) A-tile software prefetch: pack af (frees v), issue next iter's 8
//       float4 loads BEFORE the MFMA block -> load latency hides under
//       52 MFMAs + stores. Peak live ~115 regs < 128.

#define BB 16
#define NN 1024
#define MM 12
#define FF 64
#define BFE 128
#define RT (BB * NN * MM)   // 196608 bond rows
#define S_BN 0.99950037f    // 1/sqrt(1+1e-3)
#define WCOLS 208           // 192 core cols (3 layers x 64) + 3 filt + 13 pad
#define WSTR 136            // padded K stride (bf16) for bond GEMM panel
#define N_WT (WCOLS * WSTR) // 28288
#define PSTR 72             // atomproj panel K stride (bf16), 16B-aligned cols
#define PCOLS 144           // 64 w1 + 64 w2 + fw1 + fw2 + pad
#define PSZ (PCOLS * PSTR)  // 10368 shorts per (hi|lo) panel

#define N_EMB (BB * NN * FF)        // 1048576
#define N_FOLD 192
#define N_WPROJ (3 * PSZ)           // 31104
#define N_PREP (N_EMB + N_FOLD + N_WT + N_WPROJ)

typedef __attribute__((ext_vector_type(8))) short bf16x8;
typedef __attribute__((ext_vector_type(4))) float f32x4;

static __device__ __forceinline__ unsigned short f2bf(float f) {
    union { float f; unsigned u; } c; c.f = f;
    unsigned r = c.u + 0x7fff + ((c.u >> 16) & 1);   // RNE
    return (unsigned short)(r >> 16);
}
static __device__ __forceinline__ float bf2f(unsigned short s) {
    union { unsigned u; float f; } c; c.u = ((unsigned)s) << 16;
    return c.f;
}
static __device__ __forceinline__ bf16x8 pack_bf16x8(float4 a, float4 b) {
    union { unsigned u[4]; bf16x8 v; } r;
    r.u[0] = (unsigned)f2bf(a.x) | ((unsigned)f2bf(a.y) << 16);
    r.u[1] = (unsigned)f2bf(a.z) | ((unsigned)f2bf(a.w) << 16);
    r.u[2] = (unsigned)f2bf(b.x) | ((unsigned)f2bf(b.y) << 16);
    r.u[3] = (unsigned)f2bf(b.z) | ((unsigned)f2bf(b.w) << 16);
    return r.v;
}
static __device__ __forceinline__ float4 residual4(float4 v) {
    float4 r;
    r.x = v.x - bf2f(f2bf(v.x));
    r.y = v.y - bf2f(f2bf(v.y));
    r.z = v.z - bf2f(f2bf(v.z));
    r.w = v.w - bf2f(f2bf(v.w));
    return r;
}

// ---- all preprocessing in one launch ---------------------------------------
// [0,N_EMB): embedding gather -> x
// [+N_FOLD): BN-a folded core bias cbp
// [+N_WT): bond-GEMM panel wT (permuted cols, WSTR=136, linear — R3 format)
// [+N_WPROJ): atomproj hi/lo split-bf16 panels (PSTR=72)
__global__ void prep_all(const int* __restrict__ at, const float* __restrict__ emb,
                         const float* __restrict__ cw, const float* __restrict__ cb,
                         const float* __restrict__ fw, const float* __restrict__ g,
                         const float* __restrict__ bab,
                         float* __restrict__ x, float* __restrict__ cbp,
                         unsigned short* __restrict__ wT,
                         unsigned short* __restrict__ wproj) {
    int i = blockIdx.x * 256 + threadIdx.x;
    if (i < N_EMB) {
        x[i] = emb[at[i >> 6] * FF + (i & 63)];
        return;
    }
    i -= N_EMB;
    if (i < N_FOLD) {
        int f = i & 63, l = i >> 6;
        float gs = g[l * 64 + f] * S_BN;
        cbp[i] = cb[l * 64 + f] * gs + bab[l * 64 + f];
        return;
    }
    i -= N_FOLD;
    if (i < N_WT) {
        int col = i / WSTR, k = i % WSTR;
        float v = 0.f;
        if (k < 128) {
            if (col < 192) {
                int l = col >> 6, p = col & 63;
                int f = ((p & 15) << 2) | (p >> 4);       // 4*m + tt
                v = cw[(l * 256 + 128 + k) * 64 + f] * g[l * 64 + f] * S_BN;
            } else if (col < 195) {
                int l = col - 192;
                v = fw[l * 256 + 128 + k];
            }
        }
        wT[i] = f2bf(v);
        return;
    }
    i -= N_WT;
    if (i < N_WPROJ) {
        int l = i / PSZ;
        int rem = i - l * PSZ;
        int col = rem / PSTR, k = rem - col * PSTR;
        float v = 0.f;
        if (k < 64) {
            if (col < 64)
                v = cw[(l * 256 + k) * 64 + col] * g[l * 64 + col] * S_BN;
            else if (col < 128)
                v = cw[(l * 256 + 64 + k) * 64 + (col - 64)] * g[l * 64 + (col - 64)] * S_BN;
            else if (col == 128)
                v = fw[l * 256 + k];
            else if (col == 129)
                v = fw[l * 256 + 64 + k];
        }
        unsigned short hi = f2bf(v);
        wproj[(size_t)l * 2 * PSZ + col * PSTR + k] = hi;
        wproj[(size_t)l * 2 * PSZ + PSZ + col * PSTR + k] = f2bf(v - bf2f(hi));
    }
}

// ---- one-shot bf16 MFMA GEMM: core_{0,1,2} (bf16) + filt_{0,1,2} (fp32) ----
// A = bond (196608 x 128, fp32 -> bf16 in registers), B = wT (128 x 208)
// 512 blocks x 6 iters x 64 rows; panel staged once via global_load_lds;
// A-tile prefetched one iteration ahead.
__global__ __launch_bounds__(256, 2) void gemm_bond(
    const float* __restrict__ bond, const unsigned short* __restrict__ wT,
    unsigned short* __restrict__ core, float* __restrict__ filt) {
    __shared__ unsigned short bsh[WCOLS * WSTR];  // 56576 B weights
    int tid = threadIdx.x;
    int wv = tid >> 6, lane = tid & 63;
    int m = lane & 15, quad = lane >> 4;

    // stage weights ONCE via async global->LDS (no VGPR round-trip).
    // 3536 float4; per-wave dest is linear: base + lane*16 (HW pattern).
    const float4* wsrc = (const float4*)wT;
    #pragma unroll
    for (int i = 0; i < 14; i++) {
        int idx = tid + 256 * i;
        if (idx < N_WT * 2 / 16) {
            __builtin_amdgcn_global_load_lds(
                (const __attribute__((address_space(1))) unsigned int*)(wsrc + idx),
                (__attribute__((address_space(3))) unsigned int*)((char*)bsh + 16 * idx),
                16, 0, 0);
        }
    }

    int rowb = blockIdx.x * 384 + wv * 16 + m;
    float4 v[8];
    // prefetch A for it=0 (overlaps panel staging latency)
    {
        const float* ab = bond + (size_t)rowb * BFE + quad * 8;
        v[0] = *(const float4*)(ab);      v[1] = *(const float4*)(ab + 4);
        v[2] = *(const float4*)(ab + 32); v[3] = *(const float4*)(ab + 36);
        v[4] = *(const float4*)(ab + 64); v[5] = *(const float4*)(ab + 68);
        v[6] = *(const float4*)(ab + 96); v[7] = *(const float4*)(ab + 100);
    }
    __syncthreads();   // drains vmcnt: panel + first A tile resident

    #pragma unroll 1
    for (int it = 0; it < 6; it++) {
        // pack current A (frees v for the prefetch)
        bf16x8 af[4];
        af[0] = pack_bf16x8(v[0], v[1]);
        af[1] = pack_bf16x8(v[2], v[3]);
        af[2] = pack_bf16x8(v[4], v[5]);
        af[3] = pack_bf16x8(v[6], v[7]);

        // issue next iteration's A loads; latency hides under MFMAs + stores
        if (it < 5) {
            const float* ab = bond + (size_t)(rowb + (it + 1) * 64) * BFE + quad * 8;
            v[0] = *(const float4*)(ab);      v[1] = *(const float4*)(ab + 4);
            v[2] = *(const float4*)(ab + 32); v[3] = *(const float4*)(ab + 36);
            v[4] = *(const float4*)(ab + 64); v[5] = *(const float4*)(ab + 68);
            v[6] = *(const float4*)(ab + 96); v[7] = *(const float4*)(ab + 100);
        }

        f32x4 acc[13];
        #pragma unroll
        for (int t = 0; t < 13; t++) acc[t] = (f32x4){0.f, 0.f, 0.f, 0.f};

        #pragma unroll
        for (int c = 0; c < 4; c++) {
            bf16x8 a = af[c];
            #pragma unroll
            for (int t = 0; t < 13; t++) {
                bf16x8 bfv = *(const bf16x8*)&bsh[(t * 16 + m) * WSTR + c * 32 + quad * 8];
                acc[t] = __builtin_amdgcn_mfma_f32_16x16x32_bf16(a, bfv, acc[t], 0, 0, 0);
            }
        }

        int crow = rowb - m + quad * 4 + it * 64;
        #pragma unroll
        for (int l = 0; l < 3; l++) {
            #pragma unroll
            for (int r = 0; r < 4; r++) {
                ushort4 h;
                h.x = f2bf(acc[l * 4 + 0][r]);
                h.y = f2bf(acc[l * 4 + 1][r]);
                h.z = f2bf(acc[l * 4 + 2][r]);
                h.w = f2bf(acc[l * 4 + 3][r]);
                *(ushort4*)&core[((size_t)l * RT + crow + r) * 64 + 4 * m] = h;
            }
        }
        if (m < 3) {
            #pragma unroll
            for (int r = 0; r < 4; r++)
                filt[(size_t)m * RT + crow + r] = acc[12][r];
        }
    }
}

// ---- per-atom projections via MFMA (hi/lo split-bf16, ~f32 accuracy) -------
// C = x (16384x64) @ panel (64x144): cols 0..63 ys (+bias), 64..127 yn,
// 128 fs-proj (+fb), 129 fn-proj. acc = Ahi*Bhi + Alo*Bhi + Ahi*Blo.
__global__ __launch_bounds__(256) void atomproj_mfma(
    const float* __restrict__ x, const unsigned short* __restrict__ wproj_l,
    const float* __restrict__ cbp_l, const float* __restrict__ fb_l,
    float* __restrict__ ys, float* __restrict__ yn,
    float* __restrict__ fs, float* __restrict__ fn) {
    __shared__ unsigned short psh[2 * PSZ];   // 41472 B: hi panel then lo panel
    int tid = threadIdx.x, w = tid >> 6, lane = tid & 63;
    int m = lane & 15, quad = lane >> 4;

    const float4* src = (const float4*)wproj_l;
    float4* dst = (float4*)psh;
    #pragma unroll
    for (int i = 0; i < 11; i++) {
        int idx = tid + 256 * i;
        if (idx < (2 * PSZ * 2) / 16) dst[idx] = src[idx];
    }
    __syncthreads();

    int row = blockIdx.x * 64 + w * 16 + m;
    const float* xb = x + (size_t)row * 64 + quad * 8;
    bf16x8 ahi[2], alo[2];
    #pragma unroll
    for (int c = 0; c < 2; c++) {
        float4 v0 = *(const float4*)(xb + c * 32);
        float4 v1 = *(const float4*)(xb + c * 32 + 4);
        ahi[c] = pack_bf16x8(v0, v1);
        alo[c] = pack_bf16x8(residual4(v0), residual4(v1));
    }

    f32x4 acc[9];
    #pragma unroll
    for (int t = 0; t < 9; t++) acc[t] = (f32x4){0.f, 0.f, 0.f, 0.f};

    #pragma unroll
    for (int c = 0; c < 2; c++) {
        #pragma unroll
        for (int t = 0; t < 9; t++) {
            int off = (t * 16 + m) * PSTR + c * 32 + quad * 8;
            bf16x8 bh = *(const bf16x8*)&psh[off];
            bf16x8 bl = *(const bf16x8*)&psh[PSZ + off];
            acc[t] = __builtin_amdgcn_mfma_f32_16x16x32_bf16(ahi[c], bh, acc[t], 0, 0, 0);
            acc[t] = __builtin_amdgcn_mfma_f32_16x16x32_bf16(alo[c], bh, acc[t], 0, 0, 0);
            acc[t] = __builtin_amdgcn_mfma_f32_16x16x32_bf16(ahi[c], bl, acc[t], 0, 0, 0);
        }
    }

    int crow = blockIdx.x * 64 + w * 16 + quad * 4;
    #pragma unroll
    for (int t = 0; t < 4; t++) {
        float bias = cbp_l[t * 16 + m];
        #pragma unroll
        for (int r = 0; r < 4; r++)
            ys[(size_t)(crow + r) * 64 + t * 16 + m] = acc[t][r] + bias;
    }
    #pragma unroll
    for (int t = 4; t < 8; t++) {
        #pragma unroll
        for (int r = 0; r < 4; r++)
            yn[(size_t)(crow + r) * 64 + (t - 4) * 16 + m] = acc[t][r];
    }
    if (m == 0) {
        float fbv = fb_l[0];
        #pragma unroll
        for (int r = 0; r < 4; r++) fs[crow + r] = acc[8][r] + fbv;
    }
    if (m == 1) {
        #pragma unroll
        for (int r = 0; r < 4; r++) fn[crow + r] = acc[8][r];
    }
}

// ---- per-layer epilogue: softmax + weighted mean + BN-b + residual ---------
// XCD swizzle: blocks with bid%8==x (dispatched to XCD x) take contiguous
// row range [x*2048,(x+1)*2048) = 2 batches -> gathers are XCD-L2-local.
__global__ __launch_bounds__(256) void layer_ep(
    const float* __restrict__ x, const unsigned short* __restrict__ core_l,
    const float* __restrict__ filt_l, const int* __restrict__ nbr,
    const float* __restrict__ ys, const float* __restrict__ yn,
    const float* __restrict__ fs, const float* __restrict__ fn,
    const float* __restrict__ bbg, const float* __restrict__ bbb,
    float* __restrict__ xout) {
    int tid = threadIdx.x, w = tid >> 6, lane = tid & 63;
    int sb = (blockIdx.x & 7) * 512 + (blockIdx.x >> 3);   // bijective, grid 4096
    int row = sb * 4 + w;
    int base = (row >> 10) * NN;
    size_t rb = (size_t)row * MM;

    int jv[MM]; float fltv[MM], corev[MM];
    #pragma unroll
    for (int mm = 0; mm < MM; mm++) jv[mm] = nbr[rb + mm];
    float fsv = fs[row], ysv = ys[(size_t)row * 64 + lane];
    #pragma unroll
    for (int mm = 0; mm < MM; mm++)
        fltv[mm] = filt_l[rb + mm] + fsv + fn[base + jv[mm]];
    #pragma unroll
    for (int mm = 0; mm < MM; mm++)
        corev[mm] = bf2f(core_l[(rb + mm) * 64 + lane]) + ysv
                  + yn[(size_t)(base + jv[mm]) * 64 + lane];
    float fmax = -1e30f;
    #pragma unroll
    for (int mm = 0; mm < MM; mm++) fmax = fmaxf(fmax, fltv[mm]);
    float fsum = 0.f;
    #pragma unroll
    for (int mm = 0; mm < MM; mm++) { fltv[mm] = __expf(fltv[mm] - fmax); fsum += fltv[mm]; }
    float inv = 1.f / (12.f * fsum);
    float summed = 0.f;
    #pragma unroll
    for (int mm = 0; mm < MM; mm++) summed += fltv[mm] * fmaxf(corev[mm], 0.f);
    summed *= inv;
    float o = x[(size_t)row * 64 + lane] + bbg[lane] * (summed * S_BN) + bbb[lane];
    xout[(size_t)row * 64 + lane] = fmaxf(o, 0.f);
}

// ---- pooling gather + dense + relu ----------------------------------------
__global__ __launch_bounds__(256) void final_k(
    const float* __restrict__ x, const int* __restrict__ tidx,
    const float* __restrict__ dw, const float* __restrict__ db,
    float* __restrict__ out) {
    __shared__ float xs[4][64];
    __shared__ float wsh[64 * 64];
    int tid = threadIdx.x;
    int w = tid >> 6, lane = tid & 63;
    const float4* src = (const float4*)dw;
    float4* dst = (float4*)wsh;
    #pragma unroll
    for (int i = 0; i < 4; i++) dst[tid + 256 * i] = src[tid + 256 * i];
    int row = blockIdx.x * 4 + w;        // b*64 + i
    int b = row >> 6;
    int t = tidx[row];
    float xv = x[((size_t)b * NN + t) * 64 + lane];
    xs[w][lane] = fmaxf(xv, 0.f);
    __syncthreads();
    float a = db[lane];
    #pragma unroll 16
    for (int k = 0; k < 64; k++) a += xs[w][k] * wsh[k * 64 + lane];
    out[row * 64 + lane] = fmaxf(a, 0.f);
}

extern "C" void kernel_launch(void* const* d_in, const int* in_sizes, int n_in,
                              void* d_out, int out_size, void* d_ws, size_t ws_size,
                              hipStream_t stream) {
    const int*   at   = (const int*)d_in[0];
    const float* bond = (const float*)d_in[1];
    const int*   nbr  = (const int*)d_in[2];
    const int*   tgt  = (const int*)d_in[3];
    const float* emb  = (const float*)d_in[4];
    const float* cw   = (const float*)d_in[5];
    const float* cb   = (const float*)d_in[6];
    const float* fw   = (const float*)d_in[7];
    const float* fb   = (const float*)d_in[8];
    const float* bag  = (const float*)d_in[9];
    const float* bab  = (const float*)d_in[10];
    const float* bbg  = (const float*)d_in[11];
    const float* bbb  = (const float*)d_in[12];
    const float* dw   = (const float*)d_in[13];
    const float* db   = (const float*)d_in[14];

    float* ws   = (float*)d_ws;
    float* xA   = ws;
    float* xB   = xA + (size_t)BB * NN * FF;          // 1,048,576 each
    float* cwp  = xB + (size_t)BB * NN * FF;          // 49,152 (holds wproj)
    float* cbp  = cwp + 3 * 256 * 64;                 // 192
    float* ys   = cbp + 192;                          // 1,048,576
    float* yn   = ys + (size_t)BB * NN * FF;          // 1,048,576
    float* fs   = yn + (size_t)BB * NN * FF;          // 16,384
    float* fn   = fs + (size_t)BB * NN;               // 16,384
    float* filt = fn + (size_t)BB * NN;               // 3*196608 fp32
    unsigned short* wT   = (unsigned short*)(filt + 3 * (size_t)RT);  // 28,288 bf16
    unsigned short* core = wT + N_WT;                 // 3*196608*64 bf16 (~75.5 MB)
    unsigned short* wproj = (unsigned short*)cwp;     // 62,208 shorts (fits)
    // total ~95 MB

    prep_all<<<(N_PREP + 255) / 256, 256, 0, stream>>>(
        at, emb, cw, cb, fw, bag, bab, xA, cbp, wT, wproj);
    gemm_bond<<<512, 256, 0, stream>>>(bond, wT, core, filt);

    float* xin = xA;
    float* xout = xB;
    for (int l = 0; l < 3; l++) {
        atomproj_mfma<<<BB * NN / 64, 256, 0, stream>>>(
            xin, wproj + (size_t)l * 2 * PSZ, cbp + l * 64, fb + l,
            ys, yn, fs, fn);
        layer_ep<<<BB * NN / 4, 256, 0, stream>>>(
            xin, core + (size_t)l * RT * 64, filt + (size_t)l * RT, nbr,
            ys, yn, fs, fn, bbg + l * 64, bbb + l * 64, xout);
        float* t = xin; xin = xout; xout = t;
    }

    final_k<<<BB * 64 / 4, 256, 0, stream>>>(xin, tgt, dw, db, (float*)d_out);
}